// Round 3
// baseline (12368.250 us; speedup 1.0000x reference)
//
#include <hip/hip_runtime.h>
#include <stdint.h>

typedef __attribute__((ext_vector_type(8))) short short8;
typedef __attribute__((ext_vector_type(4))) float floatx4;
typedef __attribute__((ext_vector_type(2))) float float2v;
typedef unsigned short ushort_t;
typedef unsigned long long ull_t;

#define NB 256
#define NT 512
constexpr int B_ = 64, T_ = 512, D_ = 1024, H_ = 1024, O_ = 256;

// ---- ws layout (bytes) ----
constexpr size_t WS_SLOTS = 0;      // unsigned slots[4][64]
constexpr size_t WS_MODE  = 4096;   // unsigned: 1 = f32 inputs
constexpr size_t WS_HBUF  = 8192;   // bf16 hbuf[4][4][64][1024] = 2 MiB

constexpr int LDS_BYTES = 147456;   // xch[8][4][64][18] f32

__device__ __forceinline__ float bs2f(ushort_t s){
  union { unsigned u; float f; } v; v.u = ((unsigned)s) << 16; return v.f;
}
__device__ __forceinline__ ushort_t f2bs(float f){
  union { float f; unsigned u; } v; v.f = f;
  unsigned r = (v.u + 0x7fffu + ((v.u >> 16) & 1u)) >> 16;
  return (ushort_t)r;
}
__device__ __forceinline__ float sigf(float x){ return 1.f/(1.f + __expf(-x)); }
__device__ __forceinline__ float tanh_f(float x){ return 1.f - 2.f/(__expf(2.f*x) + 1.f); }
__device__ __forceinline__ short8 ldb8(const ushort_t* p){ return *(const short8*)p; }

__device__ __forceinline__ unsigned cvtpk(float lo, float hi){
  unsigned r; asm("v_cvt_pk_bf16_f32 %0, %1, %2" : "=v"(r) : "v"(lo), "v"(hi)); return r;
}
__device__ __forceinline__ short8 cvt8pk(floatx4 a, floatx4 b){
  union { unsigned u[4]; short8 s; } c;
  c.u[0] = cvtpk(a[0], a[1]); c.u[1] = cvtpk(a[2], a[3]);
  c.u[2] = cvtpk(b[0], b[1]); c.u[3] = cvtpk(b[2], b[3]);
  return c.s;
}

// system-scope (sc0 sc1) primitives: cross-XCD coherent with NO buffer_inv/wbl2.
__device__ __forceinline__ void waitge_sys(unsigned* p, int tgt){
  while ((int)__hip_atomic_load(p, __ATOMIC_RELAXED, __HIP_MEMORY_SCOPE_SYSTEM) < tgt)
    __builtin_amdgcn_s_sleep(2);
  asm volatile("" ::: "memory");
}
__device__ __forceinline__ void st_dword_sys(void* p, unsigned v){
  asm volatile("global_store_dword %0, %1, off sc0 sc1"
               :: "v"((uintptr_t)p), "v"(v) : "memory");
}
template<int AUX>
__device__ __forceinline__ void gl2lds16(const void* g, void* l){
  __builtin_amdgcn_global_load_lds(
      (const __attribute__((address_space(1))) unsigned*)g,
      (__attribute__((address_space(3))) unsigned*)l, 16, 0, AUX);
}

// ---- kernel 1: dtype sniff + slot init ----
__global__ void sniff_init(const ushort_t* __restrict__ fcb_u,
                           unsigned* __restrict__ slots, unsigned* __restrict__ mode){
  __shared__ int cnt;
  if (threadIdx.x == 0) cnt = 0;
  __syncthreads();
  slots[threadIdx.x] = 0u;
  unsigned u = fcb_u[threadIdx.x];
  unsigned e = (u >> 7) & 0xFFu;
  if (e >= 0x89u) atomicAdd(&cnt, 1);
  __syncthreads();
  if (threadIdx.x == 0) *mode = (cnt >= 4) ? 1u : 0u;
}

// ---- kernel 2: persistent pipelined LSTM ----
// 256 blocks x 512 thr; block = (layer = bx>>6, 16 h-cols). Wave w owns K-slice
// [128w,128w+128) for ALL 4 gates (A read once per block -> 1x LLC traffic).
// Register budget fix vs r2: M split into two half-passes (rows 0-31 / 32-63),
// acc[4][2]=32 VGPR + A dbuf 16 + weights 128 => ~210 VGPR, no spill at the
// mandatory 256 cap (8 waves/block => 2 waves/SIMD).
__global__ __launch_bounds__(NT, 2)
void lstm_pipe(const void* __restrict__ xv,   const void* __restrict__ Wihv,
               const void* __restrict__ Whhv, const void* __restrict__ bihv,
               const void* __restrict__ bhhv, const void* __restrict__ fcwv,
               const void* __restrict__ fcbv, void* __restrict__ outv,
               ushort_t* __restrict__ hbuf, unsigned* __restrict__ slots,
               const unsigned* __restrict__ modep)
{
  extern __shared__ char lds_raw[];
  const int tid  = threadIdx.x;
  const int bx   = blockIdx.x;
  const int lane = tid & 63;
  const int w    = tid >> 6;          // K-slice owner 0..7
  const int q    = lane >> 4;
  const int l15  = lane & 15;
  const int layer = bx >> 6;
  const int slice = bx & 63;
  const int jbase = slice * 16;

  const unsigned md = *modep;
  const bool f32in  = (md == 1u);
  const float*    xF = (const float*)xv;
  const ushort_t* xB = (const ushort_t*)xv;

  // ---- weight B-fragments: [gate][kl] for this wave's K-slice (128 VGPR) ----
  short8 wih_r[4][4], whh_r[4][4];
  {
    #pragma unroll
    for (int g = 0; g < 4; ++g){
      const size_t row = (size_t)layer*4*H_ + (size_t)g*H_ + jbase + l15;
      #pragma unroll
      for (int kl = 0; kl < 4; ++kl){
        const size_t koff = (size_t)w*128 + kl*32 + q*8;
        if (f32in){
          const float* wi = (const float*)Wihv + row*D_ + koff;
          const float* wh = (const float*)Whhv + row*H_ + koff;
          wih_r[g][kl] = cvt8pk(*(const floatx4*)wi, *(const floatx4*)(wi+4));
          whh_r[g][kl] = cvt8pk(*(const floatx4*)wh, *(const floatx4*)(wh+4));
        } else {
          wih_r[g][kl] = ldb8((const ushort_t*)Wihv + row*D_ + koff);
          whh_r[g][kl] = ldb8((const ushort_t*)Whhv + row*H_ + koff);
        }
      }
    }
  }

  // ---- pointwise mapping: thread owns (b = tid>>3, cols 2*(tid&7)+{0,1}) ----
  const int pb = tid >> 3;
  const int pj = tid & 7;
  float bsum[4][2];
  {
    #pragma unroll
    for (int g = 0; g < 4; ++g){
      const size_t idx = (size_t)layer*4*H_ + (size_t)g*H_ + jbase + 2*pj;
      if (f32in){
        bsum[g][0] = ((const float*)bihv)[idx]   + ((const float*)bhhv)[idx];
        bsum[g][1] = ((const float*)bihv)[idx+1] + ((const float*)bhhv)[idx+1];
      } else {
        bsum[g][0] = bs2f(((const ushort_t*)bihv)[idx])   + bs2f(((const ushort_t*)bhhv)[idx]);
        bsum[g][1] = bs2f(((const ushort_t*)bihv)[idx+1]) + bs2f(((const ushort_t*)bhhv)[idx+1]);
      }
    }
  }
  float c2[2] = {0.f, 0.f};

  // per-lane base offset into an h matrix, in ull (8B) units:
  // byte = l15*2048 (row) + w*256 (K-slice) + q*16
  const size_t u0 = (size_t)l15*256 + (size_t)w*32 + (size_t)q*2;

  union AFu { ull_t u[2]; short8 s; };

  // load 2 m-tiles (16B each) for K-subslice KL of half MH
  #define LD2(BUF, BASE, MH, KL) do {                                          \
    _Pragma("unroll")                                                          \
    for (int mt_ = 0; mt_ < 2; ++mt_){                                         \
      const ull_t* p_ = (BASE) + (size_t)(MH)*8192 + (size_t)mt_*4096          \
                               + u0 + (size_t)(KL)*8;                          \
      (BUF)[mt_].u[0] = __hip_atomic_load(p_,   __ATOMIC_RELAXED, __HIP_MEMORY_SCOPE_SYSTEM); \
      (BUF)[mt_].u[1] = __hip_atomic_load(p_+1, __ATOMIC_RELAXED, __HIP_MEMORY_SCOPE_SYSTEM); \
    } } while(0)

  // 8 MFMAs: 4 gates x 2 m-tiles
  #define MF2(BUF, WR, KL) do {                                                \
    _Pragma("unroll")                                                          \
    for (int g_ = 0; g_ < 4; ++g_)                                             \
      _Pragma("unroll")                                                        \
      for (int mt_ = 0; mt_ < 2; ++mt_)                                        \
        acc[g_][mt_] = __builtin_amdgcn_mfma_f32_16x16x32_bf16(                \
            (BUF)[mt_].s, (WR)[g_][(KL)], acc[g_][mt_], 0, 0, 0);              \
  } while(0)

  for (int t = 0; t < T_; ++t){
    // top waits (three wave-disjoint groups): own h_{t-1}, prev-layer h_t, ring BP
    if (t > 0 && tid < 64)                    waitge_sys(&slots[layer*64 + tid], t + 1);
    if (layer > 0 && tid >= 64 && tid < 128)  waitge_sys(&slots[(layer-1)*64 + (tid-64)], t + 2);
    if (layer < 3 && t >= 3 && tid >= 128 && tid < 192)
                                              waitge_sys(&slots[(layer+1)*64 + (tid-128)], t - 2);
    __syncthreads();                                                   // B1

    float* xch = (float*)lds_raw;
    const int wb = w*4608 + q*72 + l15;

    #pragma unroll
    for (int mh = 0; mh < 2; ++mh){
      floatx4 acc[4][2];
      #pragma unroll
      for (int g = 0; g < 4; ++g)
        #pragma unroll
        for (int mt = 0; mt < 2; ++mt) acc[g][mt] = floatx4{0.f,0.f,0.f,0.f};

      // R) recurrent GEMM from own h_{t-1} (ring slot (t-1)&3), rows mh*32..+32
      if (t > 0){
        const ull_t* hb = (const ull_t*)(hbuf + ((size_t)layer*4 + ((t+3)&3))*(size_t)(B_*H_));
        AFu A0[2], A1[2];
        LD2(A0, hb, mh, 0); LD2(A1, hb, mh, 1);
        MF2(A0, whh_r, 0);  LD2(A0, hb, mh, 2);
        MF2(A1, whh_r, 1);  LD2(A1, hb, mh, 3);
        MF2(A0, whh_r, 2);
        MF2(A1, whh_r, 3);
      }

      // I) input GEMM: prev-layer h_t (slot t&3) or x for layer 0
      if (layer > 0){
        const ull_t* ib = (const ull_t*)(hbuf + ((size_t)(layer-1)*4 + (t&3))*(size_t)(B_*H_));
        AFu A0[2], A1[2];
        LD2(A0, ib, mh, 0); LD2(A1, ib, mh, 1);
        MF2(A0, wih_r, 0);  LD2(A0, ib, mh, 2);
        MF2(A1, wih_r, 1);  LD2(A1, ib, mh, 3);
        MF2(A0, wih_r, 2);
        MF2(A1, wih_r, 3);
      } else {
        if (f32in){
          const float* xp = xF + (size_t)(mh*32 + l15)*T_*D_ + (size_t)t*D_ + w*128 + q*8;
          #pragma unroll
          for (int kl = 0; kl < 4; ++kl){
            short8 af[2];
            #pragma unroll
            for (int mt = 0; mt < 2; ++mt){
              const float* p = xp + (size_t)mt*16*T_*D_ + kl*32;
              af[mt] = cvt8pk(*(const floatx4*)p, *(const floatx4*)(p+4));
            }
            #pragma unroll
            for (int g = 0; g < 4; ++g)
              #pragma unroll
              for (int mt = 0; mt < 2; ++mt)
                acc[g][mt] = __builtin_amdgcn_mfma_f32_16x16x32_bf16(
                    af[mt], wih_r[g][kl], acc[g][mt], 0, 0, 0);
          }
        } else {
          const ushort_t* xp = xB + (size_t)(mh*32 + l15)*T_*D_ + (size_t)t*D_ + w*128 + q*8;
          #pragma unroll
          for (int kl = 0; kl < 4; ++kl){
            short8 af[2];
            #pragma unroll
            for (int mt = 0; mt < 2; ++mt)
              af[mt] = ldb8(xp + (size_t)mt*16*T_*D_ + kl*32);
            #pragma unroll
            for (int g = 0; g < 4; ++g)
              #pragma unroll
              for (int mt = 0; mt < 2; ++mt)
                acc[g][mt] = __builtin_amdgcn_mfma_f32_16x16x32_bf16(
                    af[mt], wih_r[g][kl], acc[g][mt], 0, 0, 0);
          }
        }
      }

      // E) write K-partials into wave-private xch region (no barrier needed per mh)
      #pragma unroll
      for (int g = 0; g < 4; ++g)
        #pragma unroll
        for (int mt = 0; mt < 2; ++mt)
          #pragma unroll
          for (int r = 0; r < 4; ++r)
            xch[wb + g*1152 + (mh*2 + mt)*288 + r*18] = acc[g][mt][r];
    }
    __syncthreads();                                                   // B2

    // F) reduce 8 partials + pointwise cell; pack 2 bf16 -> one sc0sc1 dword store
    {
      const float* xchc = (const float*)lds_raw;
      const int rb = pb*18 + 2*pj;
      float2v s[4] = { float2v{0.f,0.f}, float2v{0.f,0.f}, float2v{0.f,0.f}, float2v{0.f,0.f} };
      #pragma unroll
      for (int w8 = 0; w8 < 8; ++w8)
        #pragma unroll
        for (int g = 0; g < 4; ++g)
          s[g] += *(const float2v*)&xchc[w8*4608 + g*1152 + rb];

      float hv[2];
      #pragma unroll
      for (int u = 0; u < 2; ++u){
        float ig = sigf  (s[0][u] + bsum[0][u]);
        float fg = sigf  (s[1][u] + bsum[1][u]);
        float gg = tanh_f(s[2][u] + bsum[2][u]);
        float og = sigf  (s[3][u] + bsum[3][u]);
        float cn = fg*c2[u] + ig*gg;
        c2[u] = cn;
        hv[u] = og*tanh_f(cn);
      }
      unsigned pack = cvtpk(hv[0], hv[1]);
      ushort_t* hw = hbuf + ((size_t)layer*4 + (t&3))*(size_t)(B_*H_)
                   + (size_t)pb*H_ + jbase + 2*pj;
      st_dword_sys(hw, pack);
    }
    asm volatile("s_waitcnt vmcnt(0)" ::: "memory");
    __syncthreads();                                                   // B3
    if (tid == 0)
      __hip_atomic_store(&slots[layer*64 + slice], (unsigned)(t + 2),
                         __ATOMIC_RELAXED, __HIP_MEMORY_SCOPE_SYSTEM);
  }

  #undef LD2
  #undef MF2

  // ---- FC epilogue: blocks 0..63 -> batch row; LDS-stage final h ----
  if (bx < B_){
    if (tid < 64) waitge_sys(&slots[3*64 + tid], T_ + 1);
    __syncthreads();
    const char* hr = (const char*)(hbuf + (((size_t)3*4 + ((T_-1)&3))*B_ + bx)*(size_t)H_);
    if (tid < 128) gl2lds16<0x11>(hr + (size_t)tid*16, lds_raw + (size_t)tid*16);
    asm volatile("s_waitcnt vmcnt(0)" ::: "memory");
    __syncthreads();
    if (tid < O_){
      const int b = bx, o = tid;
      const short8* hh = (const short8*)lds_raw;
      if (f32in){
        float acc = ((const float*)fcbv)[o];
        const float* wr = (const float*)fcwv + (size_t)o*H_;
        for (int k8 = 0; k8 < H_/8; ++k8){
          short8 h8 = hh[k8];
          #pragma unroll
          for (int u = 0; u < 8; ++u) acc += bs2f((ushort_t)h8[u]) * wr[k8*8 + u];
        }
        ((float*)outv)[(size_t)b*O_ + o] = acc;
      } else {
        float acc = bs2f(((const ushort_t*)fcbv)[o]);
        const ushort_t* wr = (const ushort_t*)fcwv + (size_t)o*H_;
        for (int k8 = 0; k8 < H_/8; ++k8){
          short8 h8 = hh[k8];
          short8 w8 = ldb8(wr + k8*8);
          #pragma unroll
          for (int u = 0; u < 8; ++u) acc += bs2f((ushort_t)h8[u]) * bs2f((ushort_t)w8[u]);
        }
        ((ushort_t*)outv)[(size_t)b*O_ + o] = f2bs(acc);
      }
    }
  }
}

extern "C" void kernel_launch(void* const* d_in, const int* in_sizes, int n_in,
                              void* d_out, int out_size, void* d_ws, size_t ws_size,
                              hipStream_t stream){
  static bool attr_done = false;
  if (!attr_done){
    hipFuncSetAttribute(reinterpret_cast<const void*>(&lstm_pipe),
                        hipFuncAttributeMaxDynamicSharedMemorySize, LDS_BYTES);
    attr_done = true;
  }
  char* ws = (char*)d_ws;
  unsigned* slots = (unsigned*)(ws + WS_SLOTS);
  unsigned* mode  = (unsigned*)(ws + WS_MODE);
  ushort_t* hbuf  = (ushort_t*)(ws + WS_HBUF);

  sniff_init<<<1, 256, 0, stream>>>((const ushort_t*)d_in[6], slots, mode);
  lstm_pipe<<<NB, NT, LDS_BYTES, stream>>>(d_in[0], d_in[1], d_in[2], d_in[3], d_in[4],
                                           d_in[5], d_in[6], d_out, hbuf, slots, mode);
}

// Round 4
// 11678.851 us; speedup vs baseline: 1.0590x; 1.0590x over previous
//
#include <hip/hip_runtime.h>
#include <stdint.h>

typedef __attribute__((ext_vector_type(8))) short short8;
typedef __attribute__((ext_vector_type(4))) float floatx4;
typedef __attribute__((ext_vector_type(2))) float float2v;
typedef unsigned short ushort_t;

#define NB 256
#define NT 512
constexpr int B_ = 64, T_ = 512, D_ = 1024, H_ = 1024, O_ = 256;

// ---- ws layout (bytes) ----
constexpr size_t WS_SLOTS = 0;      // unsigned slots[4][64]
constexpr size_t WS_MODE  = 4096;   // unsigned: 1 = f32 inputs
constexpr size_t WS_HBUF  = 8192;   // bf16 hbuf[4][4][64][1024] = 2 MiB

constexpr int LDS_BYTES = 147456;   // xch[8][4][64][18] f32

__device__ __forceinline__ float bs2f(ushort_t s){
  union { unsigned u; float f; } v; v.u = ((unsigned)s) << 16; return v.f;
}
__device__ __forceinline__ ushort_t f2bs(float f){
  union { float f; unsigned u; } v; v.f = f;
  unsigned r = (v.u + 0x7fffu + ((v.u >> 16) & 1u)) >> 16;
  return (ushort_t)r;
}
__device__ __forceinline__ float sigf(float x){ return 1.f/(1.f + __expf(-x)); }
__device__ __forceinline__ float tanh_f(float x){ return 1.f - 2.f/(__expf(2.f*x) + 1.f); }
__device__ __forceinline__ short8 ldb8(const ushort_t* p){ return *(const short8*)p; }

__device__ __forceinline__ unsigned cvtpk(float lo, float hi){
  unsigned r; asm("v_cvt_pk_bf16_f32 %0, %1, %2" : "=v"(r) : "v"(lo), "v"(hi)); return r;
}
__device__ __forceinline__ short8 cvt8pk(floatx4 a, floatx4 b){
  union { unsigned u[4]; short8 s; } c;
  c.u[0] = cvtpk(a[0], a[1]); c.u[1] = cvtpk(a[2], a[3]);
  c.u[2] = cvtpk(b[0], b[1]); c.u[3] = cvtpk(b[2], b[3]);
  return c.s;
}

// system-scope (sc0 sc1) primitives: cross-XCD coherent with NO buffer_inv/wbl2.
__device__ __forceinline__ void waitge_sys(unsigned* p, int tgt){
  while ((int)__hip_atomic_load(p, __ATOMIC_RELAXED, __HIP_MEMORY_SCOPE_SYSTEM) < tgt)
    __builtin_amdgcn_s_sleep(2);
  asm volatile("" ::: "memory");
}
__device__ __forceinline__ void st_dword_sys(void* p, unsigned v){
  asm volatile("global_store_dword %0, %1, off sc0 sc1"
               :: "v"((uintptr_t)p), "v"(v) : "memory");
}
// pipelined L1/L2-bypassing 16B load: invisible to compiler waitcnt pass;
// consumer MUST sit behind an explicit VMW(N) (counted vmcnt + sched_barrier).
__device__ __forceinline__ short8 ld16_sc(const void* p){
  short8 r;
  asm volatile("global_load_dwordx4 %0, %1, off sc0 sc1" : "=&v"(r) : "v"(p));
  return r;
}
#define VMW(N) do{ asm volatile("s_waitcnt vmcnt(" #N ")" ::: "memory"); \
                   __builtin_amdgcn_sched_barrier(0); }while(0)

template<int AUX>
__device__ __forceinline__ void gl2lds16(const void* g, void* l){
  __builtin_amdgcn_global_load_lds(
      (const __attribute__((address_space(1))) unsigned*)g,
      (__attribute__((address_space(3))) unsigned*)l, 16, 0, AUX);
}

// ---- kernel 1: dtype sniff + slot init ----
__global__ void sniff_init(const ushort_t* __restrict__ fcb_u,
                           unsigned* __restrict__ slots, unsigned* __restrict__ mode){
  __shared__ int cnt;
  if (threadIdx.x == 0) cnt = 0;
  __syncthreads();
  slots[threadIdx.x] = 0u;
  unsigned u = fcb_u[threadIdx.x];
  unsigned e = (u >> 7) & 0xFFu;
  if (e >= 0x89u) atomicAdd(&cnt, 1);
  __syncthreads();
  if (threadIdx.x == 0) *mode = (cnt >= 4) ? 1u : 0u;
}

// ---- kernel 2: persistent pipelined LSTM ----
// 256 blocks x 512 thr; block = (layer = bx>>6, 16 h-cols). Wave w owns K-slice
// [128w,128w+128) for ALL 4 gates (A read once per block -> 1x LLC traffic).
// vs r3: h-exchange loads are burst-issued inline-asm dwordx4 sc0sc1 with
// explicit counted vmcnt (+8/+0) + sched_barrier -- pipelined LLC round trips
// instead of serialized per-atomic drains.
__global__ __launch_bounds__(NT, 2)
void lstm_pipe(const void* __restrict__ xv,   const void* __restrict__ Wihv,
               const void* __restrict__ Whhv, const void* __restrict__ bihv,
               const void* __restrict__ bhhv, const void* __restrict__ fcwv,
               const void* __restrict__ fcbv, void* __restrict__ outv,
               ushort_t* __restrict__ hbuf, unsigned* __restrict__ slots,
               const unsigned* __restrict__ modep)
{
  extern __shared__ char lds_raw[];
  const int tid  = threadIdx.x;
  const int bx   = blockIdx.x;
  const int lane = tid & 63;
  const int w    = tid >> 6;          // K-slice owner 0..7
  const int q    = lane >> 4;
  const int l15  = lane & 15;
  const int layer = bx >> 6;
  const int slice = bx & 63;
  const int jbase = slice * 16;

  const unsigned md = *modep;
  const bool f32in  = (md == 1u);
  const float*    xF = (const float*)xv;
  const ushort_t* xB = (const ushort_t*)xv;

  // ---- weight B-fragments: [gate][kl] for this wave's K-slice (128 VGPR) ----
  short8 wih_r[4][4], whh_r[4][4];
  {
    #pragma unroll
    for (int g = 0; g < 4; ++g){
      const size_t row = (size_t)layer*4*H_ + (size_t)g*H_ + jbase + l15;
      #pragma unroll
      for (int kl = 0; kl < 4; ++kl){
        const size_t koff = (size_t)w*128 + kl*32 + q*8;
        if (f32in){
          const float* wi = (const float*)Wihv + row*D_ + koff;
          const float* wh = (const float*)Whhv + row*H_ + koff;
          wih_r[g][kl] = cvt8pk(*(const floatx4*)wi, *(const floatx4*)(wi+4));
          whh_r[g][kl] = cvt8pk(*(const floatx4*)wh, *(const floatx4*)(wh+4));
        } else {
          wih_r[g][kl] = ldb8((const ushort_t*)Wihv + row*D_ + koff);
          whh_r[g][kl] = ldb8((const ushort_t*)Whhv + row*H_ + koff);
        }
      }
    }
  }

  // ---- pointwise mapping: thread owns (b = tid>>3, cols 2*(tid&7)+{0,1}) ----
  const int pb = tid >> 3;
  const int pj = tid & 7;
  float bsum[4][2];
  {
    #pragma unroll
    for (int g = 0; g < 4; ++g){
      const size_t idx = (size_t)layer*4*H_ + (size_t)g*H_ + jbase + 2*pj;
      if (f32in){
        bsum[g][0] = ((const float*)bihv)[idx]   + ((const float*)bhhv)[idx];
        bsum[g][1] = ((const float*)bihv)[idx+1] + ((const float*)bhhv)[idx+1];
      } else {
        bsum[g][0] = bs2f(((const ushort_t*)bihv)[idx])   + bs2f(((const ushort_t*)bhhv)[idx]);
        bsum[g][1] = bs2f(((const ushort_t*)bihv)[idx+1]) + bs2f(((const ushort_t*)bhhv)[idx+1]);
      }
    }
  }
  float c2[2] = {0.f, 0.f};

  // per-lane byte offset inside one h matrix [64][1024] bf16:
  const size_t hb_lane = (size_t)l15*2048 + (size_t)w*256 + (size_t)q*16;

  // 8 burst loads: 2 m-tiles x 4 K-subslices for half MH
  #define ISSUE8(AF, BASE, MH) do{                                             \
    _Pragma("unroll")                                                          \
    for (int mt_ = 0; mt_ < 2; ++mt_)                                          \
      _Pragma("unroll")                                                        \
      for (int kl_ = 0; kl_ < 4; ++kl_)                                        \
        (AF)[mt_][kl_] = ld16_sc((const char*)(BASE) + hb_lane                 \
            + (size_t)(MH)*65536 + (size_t)mt_*32768 + (size_t)kl_*64);        \
  }while(0)

  // 32 MFMAs: 4 KL x 4 gates x 2 m-tiles
  #define MF8(AF, WR) do{                                                      \
    _Pragma("unroll")                                                          \
    for (int kl_ = 0; kl_ < 4; ++kl_)                                          \
      _Pragma("unroll")                                                        \
      for (int g_ = 0; g_ < 4; ++g_)                                           \
        _Pragma("unroll")                                                      \
        for (int mt_ = 0; mt_ < 2; ++mt_)                                      \
          acc[g_][mt_] = __builtin_amdgcn_mfma_f32_16x16x32_bf16(              \
              (AF)[mt_][kl_], (WR)[g_][kl_], acc[g_][mt_], 0, 0, 0);           \
  }while(0)

  for (int t = 0; t < T_; ++t){
    // top waits (three wave-disjoint groups): own h_{t-1}, prev-layer h_t, ring BP
    if (t > 0 && tid < 64)                    waitge_sys(&slots[layer*64 + tid], t + 1);
    if (layer > 0 && tid >= 64 && tid < 128)  waitge_sys(&slots[(layer-1)*64 + (tid-64)], t + 2);
    if (layer < 3 && t >= 3 && tid >= 128 && tid < 192)
                                              waitge_sys(&slots[(layer+1)*64 + (tid-128)], t - 2);
    __syncthreads();                                                   // B1

    float* xch = (float*)lds_raw;
    const int wb = w*4608 + q*72 + l15;
    const char* hb = (const char*)hbuf + ((size_t)layer*4 + ((t+3)&3))*(size_t)(B_*H_*2);
    const char* ib = (const char*)hbuf + ((size_t)(layer-1)*4 + (t&3))*(size_t)(B_*H_*2);

    #pragma unroll
    for (int mh = 0; mh < 2; ++mh){
      floatx4 acc[4][2];
      #pragma unroll
      for (int g = 0; g < 4; ++g)
        #pragma unroll
        for (int mt = 0; mt < 2; ++mt) acc[g][mt] = floatx4{0.f,0.f,0.f,0.f};

      short8 afr[2][4], afi[2][4];

      if (t > 0){
        ISSUE8(afr, hb, mh);                 // out: 8 (oldest)
        if (layer > 0){
          ISSUE8(afi, ib, mh);               // out: 16
          VMW(8);                            // R frags ready; I in flight
          MF8(afr, whh_r);                   // I latency hides under R MFMAs
          VMW(0);
          MF8(afi, wih_r);
        } else {
          // layer 0: x section first (compiler loads) hides R latency
          if (f32in){
            const float* xp = xF + (size_t)(mh*32 + l15)*T_*D_ + (size_t)t*D_ + w*128 + q*8;
            #pragma unroll
            for (int kl = 0; kl < 4; ++kl){
              short8 af[2];
              #pragma unroll
              for (int mt = 0; mt < 2; ++mt){
                const float* p = xp + (size_t)mt*16*T_*D_ + kl*32;
                af[mt] = cvt8pk(*(const floatx4*)p, *(const floatx4*)(p+4));
              }
              #pragma unroll
              for (int g = 0; g < 4; ++g)
                #pragma unroll
                for (int mt = 0; mt < 2; ++mt)
                  acc[g][mt] = __builtin_amdgcn_mfma_f32_16x16x32_bf16(
                      af[mt], wih_r[g][kl], acc[g][mt], 0, 0, 0);
            }
          } else {
            const ushort_t* xp = xB + (size_t)(mh*32 + l15)*T_*D_ + (size_t)t*D_ + w*128 + q*8;
            #pragma unroll
            for (int kl = 0; kl < 4; ++kl){
              short8 af[2];
              #pragma unroll
              for (int mt = 0; mt < 2; ++mt)
                af[mt] = ldb8(xp + (size_t)mt*16*T_*D_ + kl*32);
              #pragma unroll
              for (int g = 0; g < 4; ++g)
                #pragma unroll
                for (int mt = 0; mt < 2; ++mt)
                  acc[g][mt] = __builtin_amdgcn_mfma_f32_16x16x32_bf16(
                      af[mt], wih_r[g][kl], acc[g][mt], 0, 0, 0);
            }
          }
          VMW(0);
          MF8(afr, whh_r);
        }
      } else {
        // t == 0: no recurrent term
        if (layer > 0){
          ISSUE8(afi, ib, mh);
          VMW(0);
          MF8(afi, wih_r);
        } else {
          if (f32in){
            const float* xp = xF + (size_t)(mh*32 + l15)*T_*D_ + w*128 + q*8;
            #pragma unroll
            for (int kl = 0; kl < 4; ++kl){
              short8 af[2];
              #pragma unroll
              for (int mt = 0; mt < 2; ++mt){
                const float* p = xp + (size_t)mt*16*T_*D_ + kl*32;
                af[mt] = cvt8pk(*(const floatx4*)p, *(const floatx4*)(p+4));
              }
              #pragma unroll
              for (int g = 0; g < 4; ++g)
                #pragma unroll
                for (int mt = 0; mt < 2; ++mt)
                  acc[g][mt] = __builtin_amdgcn_mfma_f32_16x16x32_bf16(
                      af[mt], wih_r[g][kl], acc[g][mt], 0, 0, 0);
            }
          } else {
            const ushort_t* xp = xB + (size_t)(mh*32 + l15)*T_*D_ + w*128 + q*8;
            #pragma unroll
            for (int kl = 0; kl < 4; ++kl){
              short8 af[2];
              #pragma unroll
              for (int mt = 0; mt < 2; ++mt)
                af[mt] = ldb8(xp + (size_t)mt*16*T_*D_ + kl*32);
              #pragma unroll
              for (int g = 0; g < 4; ++g)
                #pragma unroll
                for (int mt = 0; mt < 2; ++mt)
                  acc[g][mt] = __builtin_amdgcn_mfma_f32_16x16x32_bf16(
                      af[mt], wih_r[g][kl], acc[g][mt], 0, 0, 0);
            }
          }
        }
      }

      // E) write K-partials into wave-private xch region (no barrier needed per mh)
      #pragma unroll
      for (int g = 0; g < 4; ++g)
        #pragma unroll
        for (int mt = 0; mt < 2; ++mt)
          #pragma unroll
          for (int r = 0; r < 4; ++r)
            xch[wb + g*1152 + (mh*2 + mt)*288 + r*18] = acc[g][mt][r];
    }
    __syncthreads();                                                   // B2

    // F) reduce 8 partials + pointwise cell; pack 2 bf16 -> one sc0sc1 dword store
    {
      const float* xchc = (const float*)lds_raw;
      const int rb = pb*18 + 2*pj;
      float2v s[4] = { float2v{0.f,0.f}, float2v{0.f,0.f}, float2v{0.f,0.f}, float2v{0.f,0.f} };
      #pragma unroll
      for (int w8 = 0; w8 < 8; ++w8)
        #pragma unroll
        for (int g = 0; g < 4; ++g)
          s[g] += *(const float2v*)&xchc[w8*4608 + g*1152 + rb];

      float hv[2];
      #pragma unroll
      for (int u = 0; u < 2; ++u){
        float ig = sigf  (s[0][u] + bsum[0][u]);
        float fg = sigf  (s[1][u] + bsum[1][u]);
        float gg = tanh_f(s[2][u] + bsum[2][u]);
        float og = sigf  (s[3][u] + bsum[3][u]);
        float cn = fg*c2[u] + ig*gg;
        c2[u] = cn;
        hv[u] = og*tanh_f(cn);
      }
      unsigned pack = cvtpk(hv[0], hv[1]);
      ushort_t* hw = hbuf + ((size_t)layer*4 + (t&3))*(size_t)(B_*H_)
                   + (size_t)pb*H_ + jbase + 2*pj;
      st_dword_sys(hw, pack);
    }
    asm volatile("s_waitcnt vmcnt(0)" ::: "memory");
    __syncthreads();                                                   // B3
    if (tid == 0)
      __hip_atomic_store(&slots[layer*64 + slice], (unsigned)(t + 2),
                         __ATOMIC_RELAXED, __HIP_MEMORY_SCOPE_SYSTEM);
  }

  #undef ISSUE8
  #undef MF8

  // ---- FC epilogue: blocks 0..63 -> batch row; LDS-stage final h ----
  if (bx < B_){
    if (tid < 64) waitge_sys(&slots[3*64 + tid], T_ + 1);
    __syncthreads();
    const char* hr = (const char*)(hbuf + (((size_t)3*4 + ((T_-1)&3))*B_ + bx)*(size_t)H_);
    if (tid < 128) gl2lds16<0x11>(hr + (size_t)tid*16, lds_raw + (size_t)tid*16);
    asm volatile("s_waitcnt vmcnt(0)" ::: "memory");
    __syncthreads();
    if (tid < O_){
      const int b = bx, o = tid;
      const short8* hh = (const short8*)lds_raw;
      if (f32in){
        float acc = ((const float*)fcbv)[o];
        const float* wr = (const float*)fcwv + (size_t)o*H_;
        for (int k8 = 0; k8 < H_/8; ++k8){
          short8 h8 = hh[k8];
          #pragma unroll
          for (int u = 0; u < 8; ++u) acc += bs2f((ushort_t)h8[u]) * wr[k8*8 + u];
        }
        ((float*)outv)[(size_t)b*O_ + o] = acc;
      } else {
        float acc = bs2f(((const ushort_t*)fcbv)[o]);
        const ushort_t* wr = (const ushort_t*)fcwv + (size_t)o*H_;
        for (int k8 = 0; k8 < H_/8; ++k8){
          short8 h8 = hh[k8];
          short8 w8 = ldb8(wr + k8*8);
          #pragma unroll
          for (int u = 0; u < 8; ++u) acc += bs2f((ushort_t)h8[u]) * bs2f((ushort_t)w8[u]);
        }
        ((ushort_t*)outv)[(size_t)b*O_ + o] = f2bs(acc);
      }
    }
  }
}

extern "C" void kernel_launch(void* const* d_in, const int* in_sizes, int n_in,
                              void* d_out, int out_size, void* d_ws, size_t ws_size,
                              hipStream_t stream){
  static bool attr_done = false;
  if (!attr_done){
    hipFuncSetAttribute(reinterpret_cast<const void*>(&lstm_pipe),
                        hipFuncAttributeMaxDynamicSharedMemorySize, LDS_BYTES);
    attr_done = true;
  }
  char* ws = (char*)d_ws;
  unsigned* slots = (unsigned*)(ws + WS_SLOTS);
  unsigned* mode  = (unsigned*)(ws + WS_MODE);
  ushort_t* hbuf  = (ushort_t*)(ws + WS_HBUF);

  sniff_init<<<1, 256, 0, stream>>>((const ushort_t*)d_in[6], slots, mode);
  lstm_pipe<<<NB, NT, LDS_BYTES, stream>>>(d_in[0], d_in[1], d_in[2], d_in[3], d_in[4],
                                           d_in[5], d_in[6], d_out, hbuf, slots, mode);
}